// Round 8
// baseline (790.782 us; speedup 1.0000x reference)
//
#include <hip/hip_runtime.h>

typedef __attribute__((ext_vector_type(8))) short short8;
typedef __attribute__((ext_vector_type(4))) float float4_;

#define SDIM    137
#define HID     256
#define K0PAD   160     // state (137) padded to 5 k-blocks of 32
#define KAUG    416     // 256 (h) + 160 (state part)
#define MTILE   64      // rows per block: 64KB arena -> 2 blocks/CU possible
#define NTHR    512     // 8 waves = 2 row-groups x 4 col-groups

// Activations are stored pre-scaled by SCLF = 2*log2(e): tanh(x) = 1-2/(exp2(s*x)+1),
// and s*W*h = W*(s*h), so W1/W2 stay unscaled; s folds into W0p/b0p (prep), biases
// (runtime, once per GEMM), and 1/s into Waug's h-half (prep).
#define SCLF 2.8853900817779268f
#define ISCL 0.34657359027997264f

struct __attribute__((aligned(8))) U2 { unsigned x, y; };

__device__ __forceinline__ unsigned short f2bf(float f) {
  union { float f; unsigned int i; } v; v.f = f;
  return (unsigned short)((v.i + 0x8000u) >> 16);   // round-half-up
}
// pack two floats -> two bf16 in one dword (prep; round-half-up)
__device__ __forceinline__ unsigned pack_bf16(float a, float b) {
  union { float f; unsigned u; } ua, ub; ua.f = a; ub.f = b;
  return __builtin_amdgcn_perm(ub.u + 0x8000u, ua.u + 0x8000u, 0x07060302u);
}
// hot-path pack: single HW instr, RNE rounding. low16 = bf16(a), high16 = bf16(b)
__device__ __forceinline__ unsigned cvt_pk(float a, float b) {
  unsigned r;
  asm("v_cvt_pk_bf16_f32 %0, %1, %2" : "=v"(r) : "v"(a), "v"(b));
  return r;
}
__device__ __forceinline__ float lo_bf(unsigned p) {
  union { unsigned u; float f; } v; v.u = p << 16; return v.f;
}
__device__ __forceinline__ float hi_bf(unsigned p) {
  union { unsigned u; float f; } v; v.u = p & 0xFFFF0000u; return v.f;
}
// y is pre-scaled by 2*log2(e): returns s*tanh(x) where y = s*x.
__device__ __forceinline__ float stanh(float y) {
#if __has_builtin(__builtin_amdgcn_exp2f)
  float e = __builtin_amdgcn_exp2f(y);
#else
  float e = __expf(y * 0.6931471805599453f);
#endif
  float r = __builtin_amdgcn_rcpf(e + 1.f);
  return __builtin_fmaf(-2.f * SCLF, r, SCLF);
}
// LDS index (in ushorts) for activation tiles: row stride 256 els, 16B-chunk XOR swizzle.
__device__ __forceinline__ int sidx(int row, int col) {
  return row * 256 + ((((col >> 3) ^ (row & 31)) << 3) | (col & 7));
}
// B-fragment read: row, 16B-chunk index c
__device__ __forceinline__ short8 ld_x(const unsigned short* __restrict__ X, int row, int c) {
  return *(const short8*)(X + row * 256 + (((c ^ (row & 31)) << 3)));
}

struct NoEpi { __device__ void operator()(int, float4_ (&)[4]) const {} };

// K-split GEMM half over kb in [KB0, KB0+KN), wave tile = 32 rows x 64 cols
// (nt=0..1, mt=0..3). Per wave per half: KN*4 hoisted W-frags (64 VGPR at KN=4),
// 2 x KN ds_read_b128 B-frags (halved LDS-pipe load vs the 64x32 decomposition).
// Register demand ~128-144: engineered into (128,256] so the allocator's
// one-tier-below-budget landing (budget 256 from wpe(2,2)) is the 128 tier.
// [Allocator rule, R1-R7: wpe(2,2)->lands 128 (R2); wpe(4,4)/LB(,4)->lands 64,
//  spilling if demand >> 64 (R5: +25GB scratch); LB min-waves also caps HW
//  residency to 1 block/CU (R6) -- so no LB min-waves here.]
// epi(nt-1) is issued after nt's MFMAs (fused, runs in the MFMA shadow).
template<int KB0, int KN, int LDB, int BOFF, bool INIT, class EPI>
__device__ __forceinline__ void gemm_half(const unsigned short* __restrict__ X,
                                          const unsigned short* __restrict__ W,
                                          float4_ (&a)[2][4],
                                          int rm, int q, int cbase, int rbase, EPI epi)
{
  short8 wa[KN][4];
  #pragma unroll
  for (int kb = 0; kb < KN; ++kb)
    #pragma unroll
    for (int mt = 0; mt < 4; ++mt)
      wa[kb][mt] = *(const short8*)(W + (size_t)(cbase + mt * 16 + rm) * LDB
                                      + BOFF + (KB0 + kb) * 32 + q * 8);
  #pragma unroll
  for (int nt = 0; nt < 2; ++nt) {
    short8 xb[KN];
    #pragma unroll
    for (int kb = 0; kb < KN; ++kb)
      xb[kb] = ld_x(X, rbase + nt * 16 + rm, (KB0 + kb) * 4 + q);
    if constexpr (INIT) {
      #pragma unroll
      for (int mt = 0; mt < 4; ++mt) a[nt][mt] = (float4_){0.f, 0.f, 0.f, 0.f};
    }
    #pragma unroll
    for (int kb = 0; kb < KN; ++kb)
      #pragma unroll
      for (int mt = 0; mt < 4; ++mt)
        a[nt][mt] = __builtin_amdgcn_mfma_f32_16x16x32_bf16(wa[kb][mt], xb[kb], a[nt][mt], 0, 0, 0);
    if (nt > 0) epi(nt - 1, a[nt - 1]);
  }
  epi(1, a[1]);
}

// ---------------- single merged prep kernel (one launch, 128 thr/block) ----------
// Write regions are disjoint across block ranges (no cross-block ordering needed):
//   blocks [0,256):    Waug default fill (skips the patch cells), row n = blockIdx
//   blocks [256,385):  ta/lm patches + ALL of baug
//   blocks [385,641):  W0p + b0p
//   blocks [641,1665): W1b / W2b bf16 conversion
#define PB_TA   256
#define PB_W0   385
#define PB_BLK  641
#define PB_END  1665

__global__ void prep_all(const float* __restrict__ t,
                         const float* __restrict__ W0,  const float* __restrict__ b0,
                         const float* __restrict__ Wout,const float* __restrict__ bout,
                         const float* __restrict__ lm_in_w, const float* __restrict__ lm_in_b,
                         const float* __restrict__ lm_out_w,const float* __restrict__ lm_out_b,
                         const float* __restrict__ ta_in_w, const float* __restrict__ ta_in_b,
                         const float* __restrict__ ta_out_w,const float* __restrict__ ta_out_b,
                         const float* __restrict__ blkW1, const float* __restrict__ blkW2,
                         unsigned short* __restrict__ W0p,  float* __restrict__ b0p,
                         unsigned short* __restrict__ Waug, float* __restrict__ baug,
                         unsigned short* __restrict__ W1b,  unsigned short* __restrict__ W2b)
{
  const int blk = blockIdx.x;
  const int tt  = threadIdx.x;

  if (blk < PB_TA) {
    // ---- Waug default fill: h-half = Wout*ISCL (rows<137), else zeros; skip patches
    int n = blk;
    if (tt < KAUG / 4) {
      int k0 = tt * 4;
      bool patch = (k0 >= 256) && ((n < 128 && k0 < 384) ||
                                   (n >= 128 && n < 136 && k0 >= 384 && k0 < 392));
      if (!patch) {
        U2 p;
        if (k0 < 256 && n < SDIM) {
          float4_ v = *(const float4_*)(Wout + (size_t)n * 256 + k0);
          p.x = pack_bf16(v[0] * ISCL, v[1] * ISCL);
          p.y = pack_bf16(v[2] * ISCL, v[3] * ISCL);
        } else { p.x = 0u; p.y = 0u; }
        *(U2*)(Waug + (size_t)n * KAUG + k0) = p;
      }
    }
  } else if (blk < PB_W0) {
    int b = blk - PB_TA;
    if (b < 128) {
      // ta patch row n: thread s does the 128-deep dot; block also owns baug[n]
      __shared__ float red[128];
      int n = b, s = tt;
      float dot = 0.f;
      #pragma unroll 8
      for (int r = 0; r < 128; ++r)
        dot += ta_out_w[n * 128 + r] * ta_in_w[(256 + r) * 128 + s];
      Waug[(size_t)n * KAUG + 256 + s] = f2bf(0.1f * (dot - (s == n ? 1.f : 0.f)));

      red[tt] = ta_out_w[n * 128 + tt] * ta_in_b[256 + tt];
      __syncthreads();
      if (tt < 64) {
        float p = red[tt] + red[tt + 64];
        for (int off = 32; off; off >>= 1) p += __shfl_down(p, off);
        if (tt == 0) baug[n] = bout[n] + 0.1f * (p + ta_out_b[n]);
      }
    } else {
      // lm patch (8x8) + baug[128..139]
      if (tt < 64) {
        int a = tt >> 3, c = tt & 7;
        float dot = 0.f;
        #pragma unroll
        for (int r = 0; r < 8; ++r)
          dot += lm_out_w[a * 8 + r] * lm_in_w[(16 + r) * 8 + c];
        Waug[(size_t)(128 + a) * KAUG + 384 + c] = f2bf(0.1f * (dot - (a == c ? 1.f : 0.f)));
      } else if (tt < 72) {
        int a = tt - 64;
        float dot = 0.f;
        #pragma unroll
        for (int r = 0; r < 8; ++r)
          dot += lm_out_w[a * 8 + r] * lm_in_b[16 + r];
        baug[128 + a] = bout[128 + a] + 0.1f * (dot + lm_out_b[a]);
      } else if (tt == 72) {
        baug[136] = bout[136];
        baug[137] = 0.f; baug[138] = 0.f; baug[139] = 0.f;
      }
    }
  } else if (blk < PB_BLK) {
    // W0 row n: bf16 (scaled by SCLF), fold time features into bias
    int n = blk - PB_W0;
    for (int k = tt; k < K0PAD; k += 128)
      W0p[n * K0PAD + k] = (k < SDIM) ? f2bf(W0[n * 139 + k] * SCLF) : (unsigned short)0;
    if (tt == 0) {
      float tv  = t[0];
      float ang = tv * (6.2831853071795864f / 24.0f);
      float sv = __sinf(ang), cv = __cosf(ang);
      b0p[n] = SCLF * (b0[n] + W0[n * 139 + 137] * sv + W0[n * 139 + 138] * cv);
    }
  } else {
    // residual weights -> bf16, 4 floats per thread
    int i = ((blk - PB_BLK) * 128 + tt) * 4;
    const float* s; unsigned short* d;
    if (i < 262144) { s = blkW1 + i;          d = W1b + i; }
    else            { s = blkW2 + i - 262144; d = W2b + i - 262144; }
    float4_ v = *(const float4_*)s;
    U2 p; p.x = pack_bf16(v[0], v[1]); p.y = pack_bf16(v[2], v[3]);
    *(U2*)d = p;
  }
}

// ---------------- fused main kernel ----------------
// 512 thr / 8 waves, 64-row tile, 64 KiB LDS arena. Target config (never yet
// reached): VGPR=128 AND 2 blocks/CU (16 waves/CU, 4 waves/SIMD) -- physically
// legal (4x128=512 regs/SIMD; 2x64KiB<=160KiB LDS). Spelling per the R1-R7
// allocator rule: wpe(2,2) sets budget 256, allocator lands one tier below
// = 128 (demand ~128-144 keeps it there); NO launch_bounds min-waves (R6
// showed it caps HW residency at 1 block/CU).

__global__ __launch_bounds__(NTHR)
__attribute__((amdgpu_waves_per_eu(2, 2)))
void fused_odefunc(
    const float* __restrict__ state,
    const unsigned short* __restrict__ W0p,
    const float* __restrict__ b0p,
    const unsigned short* __restrict__ blkW1,
    const float* __restrict__ blkb1,
    const unsigned short* __restrict__ blkW2,
    const float* __restrict__ blkb2,
    const unsigned short* __restrict__ Waug,
    const float* __restrict__ baug,
    float* __restrict__ out)
{
  __shared__ __align__(16) unsigned short ARENA[2 * MTILE * 256];   // 64 KiB
  unsigned short* H = ARENA;                 // h tile (persists across blocks)
  unsigned short* G = ARENA + MTILE * 256;   // state / g tile (ping)

  const int tid  = threadIdx.x;
  const int lane = tid & 63;
  const int wave = tid >> 6;               // 0..7
  const int q    = lane >> 4;
  const int rm   = lane & 15;
  const int cg   = wave & 3;               // col-group: 64 out-cols
  const int rg   = wave >> 2;              // row-group: 32 batch rows
  const int cbase = cg * 64;
  const int rbase = rg * 32;
  const int row0 = blockIdx.x * MTILE;

  // ---- stage state tile (fp32 -> bf16, packed b64) -> G
  #pragma unroll 2
  for (int qd = tid; qd < MTILE * (K0PAD / 4); qd += NTHR) {   // 2560 quads
    int m  = qd / (K0PAD / 4);
    int k0 = (qd - m * (K0PAD / 4)) * 4;
    const float* sp = state + (size_t)(row0 + m) * SDIM + k0;
    float f0 = (k0     < SDIM) ? sp[0] : 0.f;
    float f1 = (k0 + 1 < SDIM) ? sp[1] : 0.f;
    float f2 = (k0 + 2 < SDIM) ? sp[2] : 0.f;
    float f3 = (k0 + 3 < SDIM) ? sp[3] : 0.f;
    U2 p; p.x = cvt_pk(f0, f1); p.y = cvt_pk(f2, f3);
    *(U2*)(&G[sidx(m, k0)]) = p;
  }
  __syncthreads();

  float4_ a[2][4];                         // persistent accumulator [nt][mt] (32 VGPRs)

  // ---- layer 0: h' = relu(W0p @ state^T) -> H   (W0p pre-scaled by SCLF)
  {
    float4_ bias[4];
    #pragma unroll
    for (int mt = 0; mt < 4; ++mt) bias[mt] = *(const float4_*)(b0p + cbase + mt * 16 + q * 4);
    gemm_half<0, 3, K0PAD, 0, true >(G, W0p, a, rm, q, cbase, rbase, NoEpi{});
    gemm_half<3, 2, K0PAD, 0, false>(G, W0p, a, rm, q, cbase, rbase,
      [&](int nt, float4_ (&a4)[4]) {
        int row = rbase + nt * 16 + rm;
        #pragma unroll
        for (int mt = 0; mt < 4; ++mt) {
          int col0 = cbase + mt * 16 + q * 4;
          float v0 = fmaxf(a4[mt][0] + bias[mt][0], 0.f);
          float v1 = fmaxf(a4[mt][1] + bias[mt][1], 0.f);
          float v2 = fmaxf(a4[mt][2] + bias[mt][2], 0.f);
          float v3 = fmaxf(a4[mt][3] + bias[mt][3], 0.f);
          U2 p; p.x = cvt_pk(v0, v1); p.y = cvt_pk(v2, v3);
          *(U2*)(&H[sidx(row, col0)]) = p;
        }
      });
  }
  __syncthreads();

  // ---- 4 residual blocks: g' = stanh(W1@h') -> G;  h' = stanh(h' + W2@g') in H
  for (int blk = 0; blk < 4; ++blk) {
    const unsigned short* W1 = blkW1 + (size_t)blk * 65536;
    const float*          b1 = blkb1 + blk * 256;
    const unsigned short* W2 = blkW2 + (size_t)blk * 65536;
    const float*          b2 = blkb2 + blk * 256;

    {
      float4_ bb[4];
      #pragma unroll
      for (int mt = 0; mt < 4; ++mt) {
        float4_ t4 = *(const float4_*)(b1 + cbase + mt * 16 + q * 4);
        bb[mt][0] = t4[0] * SCLF; bb[mt][1] = t4[1] * SCLF;
        bb[mt][2] = t4[2] * SCLF; bb[mt][3] = t4[3] * SCLF;
      }
      gemm_half<0, 4, 256, 0, true >(H, W1, a, rm, q, cbase, rbase, NoEpi{});
      gemm_half<4, 4, 256, 0, false>(H, W1, a, rm, q, cbase, rbase,
        [&](int nt, float4_ (&a4)[4]) {
          int row = rbase + nt * 16 + rm;
          #pragma unroll
          for (int mt = 0; mt < 4; ++mt) {
            int col0 = cbase + mt * 16 + q * 4;
            float g0 = stanh(a4[mt][0] + bb[mt][0]);
            float g1 = stanh(a4[mt][1] + bb[mt][1]);
            float g2 = stanh(a4[mt][2] + bb[mt][2]);
            float g3 = stanh(a4[mt][3] + bb[mt][3]);
            U2 p; p.x = cvt_pk(g0, g1); p.y = cvt_pk(g2, g3);
            *(U2*)(&G[sidx(row, col0)]) = p;
          }
        });
    }
    __syncthreads();

    {
      float4_ bb[4];
      #pragma unroll
      for (int mt = 0; mt < 4; ++mt) {
        float4_ t4 = *(const float4_*)(b2 + cbase + mt * 16 + q * 4);
        bb[mt][0] = t4[0] * SCLF; bb[mt][1] = t4[1] * SCLF;
        bb[mt][2] = t4[2] * SCLF; bb[mt][3] = t4[3] * SCLF;
      }
      gemm_half<0, 4, 256, 0, true >(G, W2, a, rm, q, cbase, rbase, NoEpi{});
      gemm_half<4, 4, 256, 0, false>(G, W2, a, rm, q, cbase, rbase,
        [&](int nt, float4_ (&a4)[4]) {
          int row = rbase + nt * 16 + rm;
          #pragma unroll
          for (int mt = 0; mt < 4; ++mt) {
            int col0 = cbase + mt * 16 + q * 4;
            int idx = sidx(row, col0);
            U2 old = *(const U2*)(&H[idx]);             // lane-owned slots (h', scaled)
            float h0 = stanh(lo_bf(old.x) + a4[mt][0] + bb[mt][0]);
            float h1 = stanh(hi_bf(old.x) + a4[mt][1] + bb[mt][1]);
            float h2 = stanh(lo_bf(old.y) + a4[mt][2] + bb[mt][2]);
            float h3 = stanh(hi_bf(old.y) + a4[mt][3] + bb[mt][3]);
            U2 p; p.x = cvt_pk(h0, h1); p.y = cvt_pk(h2, h3);
            *(U2*)(&H[idx]) = p;
          }
        });
    }
    __syncthreads();
  }

  // ---- final: out = Waug @ [h'; state]^T + baug  (Waug h-half pre-divided by SCLF)
  // Needed out-cols: 0..136 -> col-groups 0..2 (cg2's mt>=2 hits zero-rows of Waug,
  // computed but masked at store); cg3 waves idle through the GEMMs.
  // restage state -> G (G dead since last GEMM2 barrier; H-readers unaffected)
  #pragma unroll 2
  for (int qd = tid; qd < MTILE * (K0PAD / 4); qd += NTHR) {
    int m  = qd / (K0PAD / 4);
    int k0 = (qd - m * (K0PAD / 4)) * 4;
    const float* sp = state + (size_t)(row0 + m) * SDIM + k0;
    float f0 = (k0     < SDIM) ? sp[0] : 0.f;
    float f1 = (k0 + 1 < SDIM) ? sp[1] : 0.f;
    float f2 = (k0 + 2 < SDIM) ? sp[2] : 0.f;
    float f3 = (k0 + 3 < SDIM) ? sp[3] : 0.f;
    U2 p; p.x = cvt_pk(f0, f1); p.y = cvt_pk(f2, f3);
    *(U2*)(&G[sidx(m, k0)]) = p;
  }

  if (cg < 3) {                                        // h' part (k 0..255), overlaps restage
    gemm_half<0, 4, KAUG, 0, true >(H, Waug, a, rm, q, cbase, rbase, NoEpi{});
    gemm_half<4, 4, KAUG, 0, false>(H, Waug, a, rm, q, cbase, rbase, NoEpi{});
  }
  __syncthreads();                                     // G staged + H reads done
  if (cg < 3) {                                        // state part (k 256..415)
    gemm_half<0, 3, KAUG, 256, false>(G, Waug, a, rm, q, cbase, rbase, NoEpi{});
    gemm_half<3, 2, KAUG, 256, false>(G, Waug, a, rm, q, cbase, rbase,
      [&](int nt, float4_ (&a4)[4]) {
        // direct-from-register store: this lane's rows, cols cbase..cbase+63 masked <137
        float* orow = out + (size_t)(row0 + rbase + nt * 16 + rm) * SDIM;
        #pragma unroll
        for (int mt = 0; mt < 4; ++mt) {
          int col0 = cbase + mt * 16 + q * 4;
          if (col0 < 136) {
            float4_ b = *(const float4_*)(baug + col0);
            orow[col0 + 0] = a4[mt][0] + b[0];
            orow[col0 + 1] = a4[mt][1] + b[1];
            orow[col0 + 2] = a4[mt][2] + b[2];
            orow[col0 + 3] = a4[mt][3] + b[3];
          } else if (col0 == 136) {
            orow[136] = a4[mt][0] + baug[136];
          }
        }
      });
  }
  // no tail barriers: kernel ends after the masked stores
}

extern "C" void kernel_launch(void* const* d_in, const int* in_sizes, int n_in,
                              void* d_out, int out_size, void* d_ws, size_t ws_size,
                              hipStream_t stream) {
  const float* t        = (const float*)d_in[0];
  const float* state    = (const float*)d_in[1];
  const float* W0       = (const float*)d_in[2];
  const float* b0       = (const float*)d_in[3];
  const float* blkW1    = (const float*)d_in[4];
  const float* blkb1    = (const float*)d_in[5];
  const float* blkW2    = (const float*)d_in[6];
  const float* blkb2    = (const float*)d_in[7];
  const float* Wout     = (const float*)d_in[8];
  const float* bout     = (const float*)d_in[9];
  const float* lm_in_w  = (const float*)d_in[10];
  const float* lm_in_b  = (const float*)d_in[11];
  const float* lm_out_w = (const float*)d_in[12];
  const float* lm_out_b = (const float*)d_in[13];
  const float* ta_in_w  = (const float*)d_in[14];
  const float* ta_in_b  = (const float*)d_in[15];
  const float* ta_out_w = (const float*)d_in[16];
  const float* ta_out_b = (const float*)d_in[17];

  char* ws = (char*)d_ws;
  unsigned short* W0p   = (unsigned short*)ws;                   // 256*160*2   = 81920
  float*          b0p   = (float*)(ws + 81920);                  // 1024
  unsigned short* Waug  = (unsigned short*)(ws + 82944);         // 256*416*2   = 212992
  float*          baug  = (float*)(ws + 295936);                 // 1024
  unsigned short* W1b   = (unsigned short*)(ws + 296960);        // 4*256*256*2 = 524288
  unsigned short* W2b   = (unsigned short*)(ws + 821248);        // 524288  (total ~1.31 MB)

  prep_all<<<PB_END, 128, 0, stream>>>(t, W0, b0, Wout, bout,
                                       lm_in_w, lm_in_b, lm_out_w, lm_out_b,
                                       ta_in_w, ta_in_b, ta_out_w, ta_out_b,
                                       blkW1, blkW2,
                                       W0p, b0p, Waug, baug, W1b, W2b);

  int batch = in_sizes[1] / SDIM;               // 131072
  fused_odefunc<<<batch / MTILE, NTHR, 0, stream>>>(
      state, W0p, b0p, W1b, blkb1, W2b, blkb2, Waug, baug,
      (float*)d_out);
}

// Round 9
// 719.386 us; speedup vs baseline: 1.0992x; 1.0992x over previous
//
#include <hip/hip_runtime.h>

typedef __attribute__((ext_vector_type(8))) short short8;
typedef __attribute__((ext_vector_type(4))) float float4_;

#define SDIM    137
#define HID     256
#define K0PAD   160     // state (137) padded to 5 k-blocks of 32
#define KAUG    416     // 256 (h) + 160 (state part)
#define MTILE   64      // rows per block: 64KB arena -> 2 blocks/CU possible
#define NTHR    512     // 8 waves = 2 row-groups x 4 col-groups

// Activations are stored pre-scaled by SCLF = 2*log2(e): tanh(x) = 1-2/(exp2(s*x)+1),
// and s*W*h = W*(s*h), so W1/W2 stay unscaled; s folds into W0p/b0p (prep), biases
// (runtime, once per GEMM), and 1/s into Waug's h-half (prep).
#define SCLF 2.8853900817779268f
#define ISCL 0.34657359027997264f

struct __attribute__((aligned(8))) U2 { unsigned x, y; };

__device__ __forceinline__ unsigned short f2bf(float f) {
  union { float f; unsigned int i; } v; v.f = f;
  return (unsigned short)((v.i + 0x8000u) >> 16);   // round-half-up
}
// pack two floats -> two bf16 in one dword (prep; round-half-up)
__device__ __forceinline__ unsigned pack_bf16(float a, float b) {
  union { float f; unsigned u; } ua, ub; ua.f = a; ub.f = b;
  return __builtin_amdgcn_perm(ub.u + 0x8000u, ua.u + 0x8000u, 0x07060302u);
}
// hot-path pack: single HW instr, RNE rounding. low16 = bf16(a), high16 = bf16(b)
__device__ __forceinline__ unsigned cvt_pk(float a, float b) {
  unsigned r;
  asm("v_cvt_pk_bf16_f32 %0, %1, %2" : "=v"(r) : "v"(a), "v"(b));
  return r;
}
__device__ __forceinline__ float lo_bf(unsigned p) {
  union { unsigned u; float f; } v; v.u = p << 16; return v.f;
}
__device__ __forceinline__ float hi_bf(unsigned p) {
  union { unsigned u; float f; } v; v.u = p & 0xFFFF0000u; return v.f;
}
// y is pre-scaled by 2*log2(e): returns s*tanh(x) where y = s*x.
__device__ __forceinline__ float stanh(float y) {
#if __has_builtin(__builtin_amdgcn_exp2f)
  float e = __builtin_amdgcn_exp2f(y);
#else
  float e = __expf(y * 0.6931471805599453f);
#endif
  float r = __builtin_amdgcn_rcpf(e + 1.f);
  return __builtin_fmaf(-2.f * SCLF, r, SCLF);
}
// LDS index (in ushorts) for activation tiles: row stride 256 els, 16B-chunk XOR swizzle.
__device__ __forceinline__ int sidx(int row, int col) {
  return row * 256 + ((((col >> 3) ^ (row & 31)) << 3) | (col & 7));
}
// B-fragment read: row, 16B-chunk index c
__device__ __forceinline__ short8 ld_x(const unsigned short* __restrict__ X, int row, int c) {
  return *(const short8*)(X + row * 256 + (((c ^ (row & 31)) << 3)));
}

struct NoEpi { __device__ void operator()(int, float4_ (&)[4]) const {} };

// Quarter-K GEMM pass over kb in [KB0, KB0+KN), wave tile = 32 rows x 64 cols
// (nt=0..1, mt=0..3). KN=2: hoisted wa = 8 frags = 32 VGPRs per pass -- total
// demand ~110 (acc32 + wa32 + xb16 + temps). With wpe(2,4): budget 512/min=256,
// allocator's one-tier-below landing = 128 (hoist survives); max=4 lifts the HW
// residency cap to 4 waves/EU (R8 showed wpe max caps occupancy) AND removes
// any incentive to sink to the 64 tier (can't exceed max anyway).
// epi(nt-1) is issued after nt's MFMAs (fused, runs in the MFMA shadow).
template<int KB0, int KN, int LDB, int BOFF, bool INIT, class EPI>
__device__ __forceinline__ void gemm_q(const unsigned short* __restrict__ X,
                                       const unsigned short* __restrict__ W,
                                       float4_ (&a)[2][4],
                                       int rm, int q, int cbase, int rbase, EPI epi)
{
  short8 wa[KN][4];
  #pragma unroll
  for (int kb = 0; kb < KN; ++kb)
    #pragma unroll
    for (int mt = 0; mt < 4; ++mt)
      wa[kb][mt] = *(const short8*)(W + (size_t)(cbase + mt * 16 + rm) * LDB
                                      + BOFF + (KB0 + kb) * 32 + q * 8);
  #pragma unroll
  for (int nt = 0; nt < 2; ++nt) {
    short8 xb[KN];
    #pragma unroll
    for (int kb = 0; kb < KN; ++kb)
      xb[kb] = ld_x(X, rbase + nt * 16 + rm, (KB0 + kb) * 4 + q);
    if constexpr (INIT) {
      #pragma unroll
      for (int mt = 0; mt < 4; ++mt) a[nt][mt] = (float4_){0.f, 0.f, 0.f, 0.f};
    }
    #pragma unroll
    for (int kb = 0; kb < KN; ++kb)
      #pragma unroll
      for (int mt = 0; mt < 4; ++mt)
        a[nt][mt] = __builtin_amdgcn_mfma_f32_16x16x32_bf16(wa[kb][mt], xb[kb], a[nt][mt], 0, 0, 0);
    if (nt > 0) epi(nt - 1, a[nt - 1]);
  }
  epi(1, a[1]);
}

// ---------------- single merged prep kernel (one launch, 128 thr/block) ----------
// Write regions are disjoint across block ranges (no cross-block ordering needed):
//   blocks [0,256):    Waug default fill (skips the patch cells), row n = blockIdx
//   blocks [256,385):  ta/lm patches + ALL of baug
//   blocks [385,641):  W0p + b0p
//   blocks [641,1665): W1b / W2b bf16 conversion
#define PB_TA   256
#define PB_W0   385
#define PB_BLK  641
#define PB_END  1665

__global__ void prep_all(const float* __restrict__ t,
                         const float* __restrict__ W0,  const float* __restrict__ b0,
                         const float* __restrict__ Wout,const float* __restrict__ bout,
                         const float* __restrict__ lm_in_w, const float* __restrict__ lm_in_b,
                         const float* __restrict__ lm_out_w,const float* __restrict__ lm_out_b,
                         const float* __restrict__ ta_in_w, const float* __restrict__ ta_in_b,
                         const float* __restrict__ ta_out_w,const float* __restrict__ ta_out_b,
                         const float* __restrict__ blkW1, const float* __restrict__ blkW2,
                         unsigned short* __restrict__ W0p,  float* __restrict__ b0p,
                         unsigned short* __restrict__ Waug, float* __restrict__ baug,
                         unsigned short* __restrict__ W1b,  unsigned short* __restrict__ W2b)
{
  const int blk = blockIdx.x;
  const int tt  = threadIdx.x;

  if (blk < PB_TA) {
    // ---- Waug default fill: h-half = Wout*ISCL (rows<137), else zeros; skip patches
    int n = blk;
    if (tt < KAUG / 4) {
      int k0 = tt * 4;
      bool patch = (k0 >= 256) && ((n < 128 && k0 < 384) ||
                                   (n >= 128 && n < 136 && k0 >= 384 && k0 < 392));
      if (!patch) {
        U2 p;
        if (k0 < 256 && n < SDIM) {
          float4_ v = *(const float4_*)(Wout + (size_t)n * 256 + k0);
          p.x = pack_bf16(v[0] * ISCL, v[1] * ISCL);
          p.y = pack_bf16(v[2] * ISCL, v[3] * ISCL);
        } else { p.x = 0u; p.y = 0u; }
        *(U2*)(Waug + (size_t)n * KAUG + k0) = p;
      }
    }
  } else if (blk < PB_W0) {
    int b = blk - PB_TA;
    if (b < 128) {
      // ta patch row n: thread s does the 128-deep dot; block also owns baug[n]
      __shared__ float red[128];
      int n = b, s = tt;
      float dot = 0.f;
      #pragma unroll 8
      for (int r = 0; r < 128; ++r)
        dot += ta_out_w[n * 128 + r] * ta_in_w[(256 + r) * 128 + s];
      Waug[(size_t)n * KAUG + 256 + s] = f2bf(0.1f * (dot - (s == n ? 1.f : 0.f)));

      red[tt] = ta_out_w[n * 128 + tt] * ta_in_b[256 + tt];
      __syncthreads();
      if (tt < 64) {
        float p = red[tt] + red[tt + 64];
        for (int off = 32; off; off >>= 1) p += __shfl_down(p, off);
        if (tt == 0) baug[n] = bout[n] + 0.1f * (p + ta_out_b[n]);
      }
    } else {
      // lm patch (8x8) + baug[128..139]
      if (tt < 64) {
        int a = tt >> 3, c = tt & 7;
        float dot = 0.f;
        #pragma unroll
        for (int r = 0; r < 8; ++r)
          dot += lm_out_w[a * 8 + r] * lm_in_w[(16 + r) * 8 + c];
        Waug[(size_t)(128 + a) * KAUG + 384 + c] = f2bf(0.1f * (dot - (a == c ? 1.f : 0.f)));
      } else if (tt < 72) {
        int a = tt - 64;
        float dot = 0.f;
        #pragma unroll
        for (int r = 0; r < 8; ++r)
          dot += lm_out_w[a * 8 + r] * lm_in_b[16 + r];
        baug[128 + a] = bout[128 + a] + 0.1f * (dot + lm_out_b[a]);
      } else if (tt == 72) {
        baug[136] = bout[136];
        baug[137] = 0.f; baug[138] = 0.f; baug[139] = 0.f;
      }
    }
  } else if (blk < PB_BLK) {
    // W0 row n: bf16 (scaled by SCLF), fold time features into bias
    int n = blk - PB_W0;
    for (int k = tt; k < K0PAD; k += 128)
      W0p[n * K0PAD + k] = (k < SDIM) ? f2bf(W0[n * 139 + k] * SCLF) : (unsigned short)0;
    if (tt == 0) {
      float tv  = t[0];
      float ang = tv * (6.2831853071795864f / 24.0f);
      float sv = __sinf(ang), cv = __cosf(ang);
      b0p[n] = SCLF * (b0[n] + W0[n * 139 + 137] * sv + W0[n * 139 + 138] * cv);
    }
  } else {
    // residual weights -> bf16, 4 floats per thread
    int i = ((blk - PB_BLK) * 128 + tt) * 4;
    const float* s; unsigned short* d;
    if (i < 262144) { s = blkW1 + i;          d = W1b + i; }
    else            { s = blkW2 + i - 262144; d = W2b + i - 262144; }
    float4_ v = *(const float4_*)s;
    U2 p; p.x = pack_bf16(v[0], v[1]); p.y = pack_bf16(v[2], v[3]);
    *(U2*)d = p;
  }
}

// ---------------- fused main kernel ----------------
// 512 thr / 8 waves, 64-row tile, 64 KiB LDS arena. Target config: VGPR<=128 AND
// 2 blocks/CU (16 waves/CU, 4 waves/SIMD). Spelling: wpe(2,4) -- min=2 keeps the
// register budget at 256 (allocator lands one tier below = 128, hoist survives);
// max=4 lifts the residency cap (R8: wpe max caps occupancy) and removes any
// payoff for sinking to the 64-tier. No launch_bounds min-waves (R6 pathology).

__global__ __launch_bounds__(NTHR)
__attribute__((amdgpu_waves_per_eu(2, 4)))
void fused_odefunc(
    const float* __restrict__ state,
    const unsigned short* __restrict__ W0p,
    const float* __restrict__ b0p,
    const unsigned short* __restrict__ blkW1,
    const float* __restrict__ blkb1,
    const unsigned short* __restrict__ blkW2,
    const float* __restrict__ blkb2,
    const unsigned short* __restrict__ Waug,
    const float* __restrict__ baug,
    float* __restrict__ out)
{
  __shared__ __align__(16) unsigned short ARENA[2 * MTILE * 256];   // 64 KiB
  unsigned short* H = ARENA;                 // h tile (persists across blocks)
  unsigned short* G = ARENA + MTILE * 256;   // state / g tile (ping)

  const int tid  = threadIdx.x;
  const int lane = tid & 63;
  const int wave = tid >> 6;               // 0..7
  const int q    = lane >> 4;
  const int rm   = lane & 15;
  const int cg   = wave & 3;               // col-group: 64 out-cols
  const int rg   = wave >> 2;              // row-group: 32 batch rows
  const int cbase = cg * 64;
  const int rbase = rg * 32;
  const int row0 = blockIdx.x * MTILE;

  // ---- stage state tile (fp32 -> bf16, packed b64) -> G
  #pragma unroll 2
  for (int qd = tid; qd < MTILE * (K0PAD / 4); qd += NTHR) {   // 2560 quads
    int m  = qd / (K0PAD / 4);
    int k0 = (qd - m * (K0PAD / 4)) * 4;
    const float* sp = state + (size_t)(row0 + m) * SDIM + k0;
    float f0 = (k0     < SDIM) ? sp[0] : 0.f;
    float f1 = (k0 + 1 < SDIM) ? sp[1] : 0.f;
    float f2 = (k0 + 2 < SDIM) ? sp[2] : 0.f;
    float f3 = (k0 + 3 < SDIM) ? sp[3] : 0.f;
    U2 p; p.x = cvt_pk(f0, f1); p.y = cvt_pk(f2, f3);
    *(U2*)(&G[sidx(m, k0)]) = p;
  }
  __syncthreads();

  float4_ a[2][4];                         // persistent accumulator [nt][mt] (32 VGPRs)

  // ---- layer 0: h' = relu(W0p @ state^T) -> H   (W0p pre-scaled by SCLF)
  {
    float4_ bias[4];
    #pragma unroll
    for (int mt = 0; mt < 4; ++mt) bias[mt] = *(const float4_*)(b0p + cbase + mt * 16 + q * 4);
    gemm_q<0, 2, K0PAD, 0, true >(G, W0p, a, rm, q, cbase, rbase, NoEpi{});
    gemm_q<2, 2, K0PAD, 0, false>(G, W0p, a, rm, q, cbase, rbase, NoEpi{});
    gemm_q<4, 1, K0PAD, 0, false>(G, W0p, a, rm, q, cbase, rbase,
      [&](int nt, float4_ (&a4)[4]) {
        int row = rbase + nt * 16 + rm;
        #pragma unroll
        for (int mt = 0; mt < 4; ++mt) {
          int col0 = cbase + mt * 16 + q * 4;
          float v0 = fmaxf(a4[mt][0] + bias[mt][0], 0.f);
          float v1 = fmaxf(a4[mt][1] + bias[mt][1], 0.f);
          float v2 = fmaxf(a4[mt][2] + bias[mt][2], 0.f);
          float v3 = fmaxf(a4[mt][3] + bias[mt][3], 0.f);
          U2 p; p.x = cvt_pk(v0, v1); p.y = cvt_pk(v2, v3);
          *(U2*)(&H[sidx(row, col0)]) = p;
        }
      });
  }
  __syncthreads();

  // ---- 4 residual blocks: g' = stanh(W1@h') -> G;  h' = stanh(h' + W2@g') in H
  for (int blk = 0; blk < 4; ++blk) {
    const unsigned short* W1 = blkW1 + (size_t)blk * 65536;
    const float*          b1 = blkb1 + blk * 256;
    const unsigned short* W2 = blkW2 + (size_t)blk * 65536;
    const float*          b2 = blkb2 + blk * 256;

    {
      float4_ bb[4];
      #pragma unroll
      for (int mt = 0; mt < 4; ++mt) {
        float4_ t4 = *(const float4_*)(b1 + cbase + mt * 16 + q * 4);
        bb[mt][0] = t4[0] * SCLF; bb[mt][1] = t4[1] * SCLF;
        bb[mt][2] = t4[2] * SCLF; bb[mt][3] = t4[3] * SCLF;
      }
      gemm_q<0, 2, 256, 0, true >(H, W1, a, rm, q, cbase, rbase, NoEpi{});
      gemm_q<2, 2, 256, 0, false>(H, W1, a, rm, q, cbase, rbase, NoEpi{});
      gemm_q<4, 2, 256, 0, false>(H, W1, a, rm, q, cbase, rbase, NoEpi{});
      gemm_q<6, 2, 256, 0, false>(H, W1, a, rm, q, cbase, rbase,
        [&](int nt, float4_ (&a4)[4]) {
          int row = rbase + nt * 16 + rm;
          #pragma unroll
          for (int mt = 0; mt < 4; ++mt) {
            int col0 = cbase + mt * 16 + q * 4;
            float g0 = stanh(a4[mt][0] + bb[mt][0]);
            float g1 = stanh(a4[mt][1] + bb[mt][1]);
            float g2 = stanh(a4[mt][2] + bb[mt][2]);
            float g3 = stanh(a4[mt][3] + bb[mt][3]);
            U2 p; p.x = cvt_pk(g0, g1); p.y = cvt_pk(g2, g3);
            *(U2*)(&G[sidx(row, col0)]) = p;
          }
        });
    }
    __syncthreads();

    {
      float4_ bb[4];
      #pragma unroll
      for (int mt = 0; mt < 4; ++mt) {
        float4_ t4 = *(const float4_*)(b2 + cbase + mt * 16 + q * 4);
        bb[mt][0] = t4[0] * SCLF; bb[mt][1] = t4[1] * SCLF;
        bb[mt][2] = t4[2] * SCLF; bb[mt][3] = t4[3] * SCLF;
      }
      gemm_q<0, 2, 256, 0, true >(G, W2, a, rm, q, cbase, rbase, NoEpi{});
      gemm_q<2, 2, 256, 0, false>(G, W2, a, rm, q, cbase, rbase, NoEpi{});
      gemm_q<4, 2, 256, 0, false>(G, W2, a, rm, q, cbase, rbase, NoEpi{});
      gemm_q<6, 2, 256, 0, false>(G, W2, a, rm, q, cbase, rbase,
        [&](int nt, float4_ (&a4)[4]) {
          int row = rbase + nt * 16 + rm;
          #pragma unroll
          for (int mt = 0; mt < 4; ++mt) {
            int col0 = cbase + mt * 16 + q * 4;
            int idx = sidx(row, col0);
            U2 old = *(const U2*)(&H[idx]);             // lane-owned slots (h', scaled)
            float h0 = stanh(lo_bf(old.x) + a4[mt][0] + bb[mt][0]);
            float h1 = stanh(hi_bf(old.x) + a4[mt][1] + bb[mt][1]);
            float h2 = stanh(lo_bf(old.y) + a4[mt][2] + bb[mt][2]);
            float h3 = stanh(hi_bf(old.y) + a4[mt][3] + bb[mt][3]);
            U2 p; p.x = cvt_pk(h0, h1); p.y = cvt_pk(h2, h3);
            *(U2*)(&H[idx]) = p;
          }
        });
    }
    __syncthreads();
  }

  // ---- final: out = Waug @ [h'; state]^T + baug  (Waug h-half pre-divided by SCLF)
  // Needed out-cols: 0..136 -> col-groups 0..2 (cg2's mt>=2 hits zero-rows of Waug,
  // computed but masked at store); cg3 waves idle through the GEMMs.
  // restage state -> G (G dead since last GEMM2 barrier; H-readers unaffected)
  #pragma unroll 2
  for (int qd = tid; qd < MTILE * (K0PAD / 4); qd += NTHR) {
    int m  = qd / (K0PAD / 4);
    int k0 = (qd - m * (K0PAD / 4)) * 4;
    const float* sp = state + (size_t)(row0 + m) * SDIM + k0;
    float f0 = (k0     < SDIM) ? sp[0] : 0.f;
    float f1 = (k0 + 1 < SDIM) ? sp[1] : 0.f;
    float f2 = (k0 + 2 < SDIM) ? sp[2] : 0.f;
    float f3 = (k0 + 3 < SDIM) ? sp[3] : 0.f;
    U2 p; p.x = cvt_pk(f0, f1); p.y = cvt_pk(f2, f3);
    *(U2*)(&G[sidx(m, k0)]) = p;
  }

  if (cg < 3) {                                        // h' part (k 0..255), overlaps restage
    gemm_q<0, 2, KAUG, 0, true >(H, Waug, a, rm, q, cbase, rbase, NoEpi{});
    gemm_q<2, 2, KAUG, 0, false>(H, Waug, a, rm, q, cbase, rbase, NoEpi{});
    gemm_q<4, 2, KAUG, 0, false>(H, Waug, a, rm, q, cbase, rbase, NoEpi{});
    gemm_q<6, 2, KAUG, 0, false>(H, Waug, a, rm, q, cbase, rbase, NoEpi{});
  }
  __syncthreads();                                     // G staged + H reads done
  if (cg < 3) {                                        // state part (k 256..415)
    gemm_q<0, 2, KAUG, 256, false>(G, Waug, a, rm, q, cbase, rbase, NoEpi{});
    gemm_q<2, 2, KAUG, 256, false>(G, Waug, a, rm, q, cbase, rbase, NoEpi{});
    gemm_q<4, 1, KAUG, 256, false>(G, Waug, a, rm, q, cbase, rbase,
      [&](int nt, float4_ (&a4)[4]) {
        // direct-from-register store: this lane's rows, cols cbase..cbase+63 masked <137
        float* orow = out + (size_t)(row0 + rbase + nt * 16 + rm) * SDIM;
        #pragma unroll
        for (int mt = 0; mt < 4; ++mt) {
          int col0 = cbase + mt * 16 + q * 4;
          if (col0 < 136) {
            float4_ b = *(const float4_*)(baug + col0);
            orow[col0 + 0] = a4[mt][0] + b[0];
            orow[col0 + 1] = a4[mt][1] + b[1];
            orow[col0 + 2] = a4[mt][2] + b[2];
            orow[col0 + 3] = a4[mt][3] + b[3];
          } else if (col0 == 136) {
            orow[136] = a4[mt][0] + baug[136];
          }
        }
      });
  }
  // no tail barriers: kernel ends after the masked stores
}

extern "C" void kernel_launch(void* const* d_in, const int* in_sizes, int n_in,
                              void* d_out, int out_size, void* d_ws, size_t ws_size,
                              hipStream_t stream) {
  const float* t        = (const float*)d_in[0];
  const float* state    = (const float*)d_in[1];
  const float* W0       = (const float*)d_in[2];
  const float* b0       = (const float*)d_in[3];
  const float* blkW1    = (const float*)d_in[4];
  const float* blkb1    = (const float*)d_in[5];
  const float* blkW2    = (const float*)d_in[6];
  const float* blkb2    = (const float*)d_in[7];
  const float* Wout     = (const float*)d_in[8];
  const float* bout     = (const float*)d_in[9];
  const float* lm_in_w  = (const float*)d_in[10];
  const float* lm_in_b  = (const float*)d_in[11];
  const float* lm_out_w = (const float*)d_in[12];
  const float* lm_out_b = (const float*)d_in[13];
  const float* ta_in_w  = (const float*)d_in[14];
  const float* ta_in_b  = (const float*)d_in[15];
  const float* ta_out_w = (const float*)d_in[16];
  const float* ta_out_b = (const float*)d_in[17];

  char* ws = (char*)d_ws;
  unsigned short* W0p   = (unsigned short*)ws;                   // 256*160*2   = 81920
  float*          b0p   = (float*)(ws + 81920);                  // 1024
  unsigned short* Waug  = (unsigned short*)(ws + 82944);         // 256*416*2   = 212992
  float*          baug  = (float*)(ws + 295936);                 // 1024
  unsigned short* W1b   = (unsigned short*)(ws + 296960);        // 4*256*256*2 = 524288
  unsigned short* W2b   = (unsigned short*)(ws + 821248);        // 524288  (total ~1.31 MB)

  prep_all<<<PB_END, 128, 0, stream>>>(t, W0, b0, Wout, bout,
                                       lm_in_w, lm_in_b, lm_out_w, lm_out_b,
                                       ta_in_w, ta_in_b, ta_out_w, ta_out_b,
                                       blkW1, blkW2,
                                       W0p, b0p, Waug, baug, W1b, W2b);

  int batch = in_sizes[1] / SDIM;               // 131072
  fused_odefunc<<<batch / MTILE, NTHR, 0, stream>>>(
      state, W0p, b0p, W1b, blkb1, W2b, blkb2, Waug, baug,
      (float*)d_out);
}

// Round 10
// 453.966 us; speedup vs baseline: 1.7419x; 1.5847x over previous
//
#include <hip/hip_runtime.h>

typedef __attribute__((ext_vector_type(8))) short short8;
typedef __attribute__((ext_vector_type(4))) float float4_;

#define SDIM    137
#define HID     256
#define K0PAD   160     // state (137) padded to 5 k-blocks of 32
#define KAUG    416     // 256 (h) + 160 (state part)
#define MTILE   128     // rows per block (R2 geometry -- the proven 128-VGPR point)
#define NROWT   (MTILE / 16)
#define NTHR    512     // 8 waves; each wave owns a 32-out-col strip x all 128 rows

// Activations are stored pre-scaled by SCLF = 2*log2(e): tanh(x) = 1-2/(exp2(s*x)+1),
// and s*W*h = W*(s*h), so W1/W2 stay unscaled; s folds into W0p/b0p (prep), biases
// (runtime, once per GEMM), and 1/s into Waug's h-half (prep).
#define SCLF 2.8853900817779268f
#define ISCL 0.34657359027997264f

struct __attribute__((aligned(8))) U2 { unsigned x, y; };

__device__ __forceinline__ unsigned short f2bf(float f) {
  union { float f; unsigned int i; } v; v.f = f;
  return (unsigned short)((v.i + 0x8000u) >> 16);   // round-half-up
}
// pack two floats -> two bf16 in one dword (prep; round-half-up)
__device__ __forceinline__ unsigned pack_bf16(float a, float b) {
  union { float f; unsigned u; } ua, ub; ua.f = a; ub.f = b;
  return __builtin_amdgcn_perm(ub.u + 0x8000u, ua.u + 0x8000u, 0x07060302u);
}
// hot-path pack: single HW instr, RNE rounding. low16 = bf16(a), high16 = bf16(b)
__device__ __forceinline__ unsigned cvt_pk(float a, float b) {
  unsigned r;
  asm("v_cvt_pk_bf16_f32 %0, %1, %2" : "=v"(r) : "v"(a), "v"(b));
  return r;
}
__device__ __forceinline__ float lo_bf(unsigned p) {
  union { unsigned u; float f; } v; v.u = p << 16; return v.f;
}
__device__ __forceinline__ float hi_bf(unsigned p) {
  union { unsigned u; float f; } v; v.u = p & 0xFFFF0000u; return v.f;
}
// y is pre-scaled by 2*log2(e): returns s*tanh(x) where y = s*x.
__device__ __forceinline__ float stanh(float y) {
#if __has_builtin(__builtin_amdgcn_exp2f)
  float e = __builtin_amdgcn_exp2f(y);
#else
  float e = __expf(y * 0.6931471805599453f);
#endif
  float r = __builtin_amdgcn_rcpf(e + 1.f);
  return __builtin_fmaf(-2.f * SCLF, r, SCLF);
}
// LDS index (in ushorts) for activation tiles: row stride 256 els, 16B-chunk XOR swizzle.
__device__ __forceinline__ int sidx(int row, int col) {
  return row * 256 + ((((col >> 3) ^ (row & 31)) << 3) | (col & 7));
}
// B-fragment read: row, 16B-chunk index c
__device__ __forceinline__ short8 ld_x(const unsigned short* __restrict__ X, int row, int c) {
  return *(const short8*)(X + row * 256 + (((c ^ (row & 31)) << 3)));
}

// hoist the wave's full W strip (32 cols x NK*32 k) into registers: 2*NK x 16B loads
template<int NK, int LDB, int BOFF>
__device__ __forceinline__ void load_wa(const unsigned short* __restrict__ W,
                                        short8 (&wa)[NK][2], int colbase, int rm, int q)
{
  #pragma unroll
  for (int kb = 0; kb < NK; ++kb)
    #pragma unroll
    for (int mt = 0; mt < 2; ++mt)
      wa[kb][mt] = *(const short8*)(W + (size_t)(colbase + mt * 16 + rm) * LDB
                                      + BOFF + kb * 32 + q * 8);
}

// nt-outer fused GEMM (the R2 structure -- the only one the allocator grants 128
// clean VGPRs): full W-strip hoist, then per 16-row tile: ds_reads + MFMA chain,
// then the PREVIOUS tile's pure-VALU epilogue runs in the MFMA shadow.
template<int NK, class EPI>
__device__ __forceinline__ void gemm_f(const unsigned short* __restrict__ X,
                                       const short8 (&wa)[NK][2],
                                       int rm, int q, EPI epi)
{
  float4_ a[NROWT][2];
  #pragma unroll
  for (int nt = 0; nt < NROWT; ++nt) {
    short8 xb[NK];
    #pragma unroll
    for (int kb = 0; kb < NK; ++kb) xb[kb] = ld_x(X, nt * 16 + rm, kb * 4 + q);
    a[nt][0] = (float4_){0.f, 0.f, 0.f, 0.f};
    a[nt][1] = (float4_){0.f, 0.f, 0.f, 0.f};
    #pragma unroll
    for (int kb = 0; kb < NK; ++kb) {
      a[nt][0] = __builtin_amdgcn_mfma_f32_16x16x32_bf16(wa[kb][0], xb[kb], a[nt][0], 0, 0, 0);
      a[nt][1] = __builtin_amdgcn_mfma_f32_16x16x32_bf16(wa[kb][1], xb[kb], a[nt][1], 0, 0, 0);
    }
    if (nt > 0) epi(nt - 1, a[nt - 1]);
  }
  epi(NROWT - 1, a[NROWT - 1]);
}

// kb-outer accumulating path (final GEMM: two passes over H then G into one acc)
template<int NK, int LDB, int BOFF>
__device__ __forceinline__ void mma_wact(const unsigned short* __restrict__ X,
                                         const unsigned short* __restrict__ W,
                                         float4_ (&acc)[2][NROWT], int lane, int colbase)
{
  const int q  = lane >> 4;
  const int rm = lane & 15;
  short8 wa[NK][2];
  load_wa<NK, LDB, BOFF>(W, wa, colbase, rm, q);
  #pragma unroll
  for (int kb = 0; kb < NK; ++kb) {
    short8 xb[NROWT];
    #pragma unroll
    for (int nt = 0; nt < NROWT; ++nt)
      xb[nt] = ld_x(X, nt * 16 + rm, kb * 4 + q);
    #pragma unroll
    for (int mt = 0; mt < 2; ++mt)
      #pragma unroll
      for (int nt = 0; nt < NROWT; ++nt)
        acc[mt][nt] = __builtin_amdgcn_mfma_f32_16x16x32_bf16(wa[kb][mt], xb[nt], acc[mt][nt], 0, 0, 0);
  }
}

// ---------------- single merged prep kernel (one launch, 128 thr/block) ----------
// Write regions are disjoint across block ranges (no cross-block ordering needed):
//   blocks [0,256):    Waug default fill (skips the patch cells), row n = blockIdx
//   blocks [256,385):  ta/lm patches + ALL of baug
//   blocks [385,641):  W0p + b0p
//   blocks [641,1665): W1b / W2b bf16 conversion
#define PB_TA   256
#define PB_W0   385
#define PB_BLK  641
#define PB_END  1665

__global__ void prep_all(const float* __restrict__ t,
                         const float* __restrict__ W0,  const float* __restrict__ b0,
                         const float* __restrict__ Wout,const float* __restrict__ bout,
                         const float* __restrict__ lm_in_w, const float* __restrict__ lm_in_b,
                         const float* __restrict__ lm_out_w,const float* __restrict__ lm_out_b,
                         const float* __restrict__ ta_in_w, const float* __restrict__ ta_in_b,
                         const float* __restrict__ ta_out_w,const float* __restrict__ ta_out_b,
                         const float* __restrict__ blkW1, const float* __restrict__ blkW2,
                         unsigned short* __restrict__ W0p,  float* __restrict__ b0p,
                         unsigned short* __restrict__ Waug, float* __restrict__ baug,
                         unsigned short* __restrict__ W1b,  unsigned short* __restrict__ W2b)
{
  const int blk = blockIdx.x;
  const int tt  = threadIdx.x;

  if (blk < PB_TA) {
    // ---- Waug default fill: h-half = Wout*ISCL (rows<137), else zeros; skip patches
    int n = blk;
    if (tt < KAUG / 4) {
      int k0 = tt * 4;
      bool patch = (k0 >= 256) && ((n < 128 && k0 < 384) ||
                                   (n >= 128 && n < 136 && k0 >= 384 && k0 < 392));
      if (!patch) {
        U2 p;
        if (k0 < 256 && n < SDIM) {
          float4_ v = *(const float4_*)(Wout + (size_t)n * 256 + k0);
          p.x = pack_bf16(v[0] * ISCL, v[1] * ISCL);
          p.y = pack_bf16(v[2] * ISCL, v[3] * ISCL);
        } else { p.x = 0u; p.y = 0u; }
        *(U2*)(Waug + (size_t)n * KAUG + k0) = p;
      }
    }
  } else if (blk < PB_W0) {
    int b = blk - PB_TA;
    if (b < 128) {
      // ta patch row n: thread s does the 128-deep dot; block also owns baug[n]
      __shared__ float red[128];
      int n = b, s = tt;
      float dot = 0.f;
      #pragma unroll 8
      for (int r = 0; r < 128; ++r)
        dot += ta_out_w[n * 128 + r] * ta_in_w[(256 + r) * 128 + s];
      Waug[(size_t)n * KAUG + 256 + s] = f2bf(0.1f * (dot - (s == n ? 1.f : 0.f)));

      red[tt] = ta_out_w[n * 128 + tt] * ta_in_b[256 + tt];
      __syncthreads();
      if (tt < 64) {
        float p = red[tt] + red[tt + 64];
        for (int off = 32; off; off >>= 1) p += __shfl_down(p, off);
        if (tt == 0) baug[n] = bout[n] + 0.1f * (p + ta_out_b[n]);
      }
    } else {
      // lm patch (8x8) + baug[128..139]
      if (tt < 64) {
        int a = tt >> 3, c = tt & 7;
        float dot = 0.f;
        #pragma unroll
        for (int r = 0; r < 8; ++r)
          dot += lm_out_w[a * 8 + r] * lm_in_w[(16 + r) * 8 + c];
        Waug[(size_t)(128 + a) * KAUG + 384 + c] = f2bf(0.1f * (dot - (a == c ? 1.f : 0.f)));
      } else if (tt < 72) {
        int a = tt - 64;
        float dot = 0.f;
        #pragma unroll
        for (int r = 0; r < 8; ++r)
          dot += lm_out_w[a * 8 + r] * lm_in_b[16 + r];
        baug[128 + a] = bout[128 + a] + 0.1f * (dot + lm_out_b[a]);
      } else if (tt == 72) {
        baug[136] = bout[136];
        baug[137] = 0.f; baug[138] = 0.f; baug[139] = 0.f;
      }
    }
  } else if (blk < PB_BLK) {
    // W0 row n: bf16 (scaled by SCLF), fold time features into bias
    int n = blk - PB_W0;
    for (int k = tt; k < K0PAD; k += 128)
      W0p[n * K0PAD + k] = (k < SDIM) ? f2bf(W0[n * 139 + k] * SCLF) : (unsigned short)0;
    if (tt == 0) {
      float tv  = t[0];
      float ang = tv * (6.2831853071795864f / 24.0f);
      float sv = __sinf(ang), cv = __cosf(ang);
      b0p[n] = SCLF * (b0[n] + W0[n * 139 + 137] * sv + W0[n * 139 + 138] * cv);
    }
  } else {
    // residual weights -> bf16, 4 floats per thread
    int i = ((blk - PB_BLK) * 128 + tt) * 4;
    const float* s; unsigned short* d;
    if (i < 262144) { s = blkW1 + i;          d = W1b + i; }
    else            { s = blkW2 + i - 262144; d = W2b + i - 262144; }
    float4_ v = *(const float4_*)s;
    U2 p; p.x = pack_bf16(v[0], v[1]); p.y = pack_bf16(v[2], v[3]);
    *(U2*)d = p;
  }
}

// ---------------- fused main kernel ----------------
// R2's exact configuration -- LB(512,2) + wpe(2,2), MTILE=128, 128 KiB arena,
// full-hoist nt-outer GEMM. This is the only point the allocator ever granted a
// clean 128 VGPRs (R2: 344 us fused, FETCH 66 GB, no spill). Changes vs R2 are
// strictly work-removal: merged prep (1 launch), direct-from-register final
// store (no fp32 T-tile round-trip, no copy loop, no tail barriers).

__global__ __launch_bounds__(NTHR, 2)
__attribute__((amdgpu_waves_per_eu(2, 2)))
void fused_odefunc(
    const float* __restrict__ state,
    const unsigned short* __restrict__ W0p,
    const float* __restrict__ b0p,
    const unsigned short* __restrict__ blkW1,
    const float* __restrict__ blkb1,
    const unsigned short* __restrict__ blkW2,
    const float* __restrict__ blkb2,
    const unsigned short* __restrict__ Waug,
    const float* __restrict__ baug,
    float* __restrict__ out)
{
  __shared__ __align__(16) unsigned short ARENA[2 * MTILE * 256];   // 128 KiB
  unsigned short* H = ARENA;                 // h tile (persists across blocks)
  unsigned short* G = ARENA + MTILE * 256;   // state / g tile (ping)

  const int tid  = threadIdx.x;
  const int lane = tid & 63;
  const int wave = tid >> 6;               // 0..7
  const int q    = lane >> 4;
  const int rm   = lane & 15;
  const int cb   = wave * 32;              // this wave's out-col base
  const int row0 = blockIdx.x * MTILE;

  // ---- stage state tile (fp32 -> bf16, packed b64) -> G
  #pragma unroll 2
  for (int qd = tid; qd < MTILE * (K0PAD / 4); qd += NTHR) {   // 5120 quads
    int m  = qd / (K0PAD / 4);
    int k0 = (qd - m * (K0PAD / 4)) * 4;
    const float* sp = state + (size_t)(row0 + m) * SDIM + k0;
    float f0 = (k0     < SDIM) ? sp[0] : 0.f;
    float f1 = (k0 + 1 < SDIM) ? sp[1] : 0.f;
    float f2 = (k0 + 2 < SDIM) ? sp[2] : 0.f;
    float f3 = (k0 + 3 < SDIM) ? sp[3] : 0.f;
    U2 p; p.x = cvt_pk(f0, f1); p.y = cvt_pk(f2, f3);
    *(U2*)(&G[sidx(m, k0)]) = p;
  }
  __syncthreads();

  // ---- layer 0: h' = relu(W0p @ state^T) -> H   (W0p pre-scaled by SCLF)
  {
    short8 wa[K0PAD / 32][2];
    load_wa<K0PAD / 32, K0PAD, 0>(W0p, wa, cb, rm, q);
    float4_ bias[2];
    #pragma unroll
    for (int mt = 0; mt < 2; ++mt) bias[mt] = *(const float4_*)(b0p + cb + mt * 16 + q * 4);
    gemm_f<K0PAD / 32>(G, wa, rm, q, [&](int nt, float4_ (&a2)[2]) {
      int row = nt * 16 + rm;
      #pragma unroll
      for (int mt = 0; mt < 2; ++mt) {
        int col0 = cb + mt * 16 + q * 4;
        float v0 = fmaxf(a2[mt][0] + bias[mt][0], 0.f);
        float v1 = fmaxf(a2[mt][1] + bias[mt][1], 0.f);
        float v2 = fmaxf(a2[mt][2] + bias[mt][2], 0.f);
        float v3 = fmaxf(a2[mt][3] + bias[mt][3], 0.f);
        U2 p; p.x = cvt_pk(v0, v1); p.y = cvt_pk(v2, v3);
        *(U2*)(&H[sidx(row, col0)]) = p;
      }
    });
  }
  __syncthreads();

  // ---- 4 residual blocks: g' = stanh(W1@h') -> G;  h' = stanh(h' + W2@g') in H
  for (int blk = 0; blk < 4; ++blk) {
    const unsigned short* W1 = blkW1 + (size_t)blk * 65536;
    const float*          b1 = blkb1 + blk * 256;
    const unsigned short* W2 = blkW2 + (size_t)blk * 65536;
    const float*          b2 = blkb2 + blk * 256;

    {
      short8 wa[8][2];
      load_wa<8, 256, 0>(W1, wa, cb, rm, q);
      float4_ bb[2];
      #pragma unroll
      for (int mt = 0; mt < 2; ++mt) {
        float4_ t4 = *(const float4_*)(b1 + cb + mt * 16 + q * 4);
        bb[mt][0] = t4[0] * SCLF; bb[mt][1] = t4[1] * SCLF;
        bb[mt][2] = t4[2] * SCLF; bb[mt][3] = t4[3] * SCLF;
      }
      gemm_f<8>(H, wa, rm, q, [&](int nt, float4_ (&a2)[2]) {
        int row = nt * 16 + rm;
        #pragma unroll
        for (int mt = 0; mt < 2; ++mt) {
          int col0 = cb + mt * 16 + q * 4;
          float g0 = stanh(a2[mt][0] + bb[mt][0]);
          float g1 = stanh(a2[mt][1] + bb[mt][1]);
          float g2 = stanh(a2[mt][2] + bb[mt][2]);
          float g3 = stanh(a2[mt][3] + bb[mt][3]);
          U2 p; p.x = cvt_pk(g0, g1); p.y = cvt_pk(g2, g3);
          *(U2*)(&G[sidx(row, col0)]) = p;
        }
      });
    }
    __syncthreads();

    {
      short8 wa[8][2];
      load_wa<8, 256, 0>(W2, wa, cb, rm, q);
      float4_ bb[2];
      #pragma unroll
      for (int mt = 0; mt < 2; ++mt) {
        float4_ t4 = *(const float4_*)(b2 + cb + mt * 16 + q * 4);
        bb[mt][0] = t4[0] * SCLF; bb[mt][1] = t4[1] * SCLF;
        bb[mt][2] = t4[2] * SCLF; bb[mt][3] = t4[3] * SCLF;
      }
      gemm_f<8>(G, wa, rm, q, [&](int nt, float4_ (&a2)[2]) {
        int row = nt * 16 + rm;
        #pragma unroll
        for (int mt = 0; mt < 2; ++mt) {
          int col0 = cb + mt * 16 + q * 4;
          int idx = sidx(row, col0);
          U2 old = *(const U2*)(&H[idx]);               // lane-owned slots (h', scaled)
          float h0 = stanh(lo_bf(old.x) + a2[mt][0] + bb[mt][0]);
          float h1 = stanh(hi_bf(old.x) + a2[mt][1] + bb[mt][1]);
          float h2 = stanh(lo_bf(old.y) + a2[mt][2] + bb[mt][2]);
          float h3 = stanh(hi_bf(old.y) + a2[mt][3] + bb[mt][3]);
          U2 p; p.x = cvt_pk(h0, h1); p.y = cvt_pk(h2, h3);
          *(U2*)(&H[idx]) = p;
        }
      });
    }
    __syncthreads();
  }

  // ---- final: out = Waug @ [h'; state]^T + baug  (Waug h-half pre-divided by SCLF)
  // restage state -> G (G dead since last GEMM2 barrier); its global-load latency
  // overlaps the h-part GEMM below (no barrier in between).
  #pragma unroll 2
  for (int qd = tid; qd < MTILE * (K0PAD / 4); qd += NTHR) {
    int m  = qd / (K0PAD / 4);
    int k0 = (qd - m * (K0PAD / 4)) * 4;
    const float* sp = state + (size_t)(row0 + m) * SDIM + k0;
    float f0 = (k0     < SDIM) ? sp[0] : 0.f;
    float f1 = (k0 + 1 < SDIM) ? sp[1] : 0.f;
    float f2 = (k0 + 2 < SDIM) ? sp[2] : 0.f;
    float f3 = (k0 + 3 < SDIM) ? sp[3] : 0.f;
    U2 p; p.x = cvt_pk(f0, f1); p.y = cvt_pk(f2, f3);
    *(U2*)(&G[sidx(m, k0)]) = p;
  }

  float4_ acc[2][NROWT];
  #pragma unroll
  for (int mt = 0; mt < 2; ++mt)
    #pragma unroll
    for (int nt = 0; nt < NROWT; ++nt) acc[mt][nt] = (float4_){0.f, 0.f, 0.f, 0.f};
  if (cb < 160)
    mma_wact<8, KAUG, 0>(H, Waug, acc, lane, cb);        // h' part (k 0..255)
  __syncthreads();                                       // G staged + H reads done
  if (cb < 160) {
    mma_wact<5, KAUG, 256>(G, Waug, acc, lane, cb);      // state part (k 256..415)
    // direct-from-register store: this lane's rows, cols cb..cb+31 masked to <137
    #pragma unroll
    for (int nt = 0; nt < NROWT; ++nt) {
      float* orow = out + (size_t)(row0 + nt * 16 + rm) * SDIM;
      #pragma unroll
      for (int mt = 0; mt < 2; ++mt) {
        int col0 = cb + mt * 16 + q * 4;
        if (col0 < 136) {
          float4_ b = *(const float4_*)(baug + col0);
          orow[col0 + 0] = acc[mt][nt][0] + b[0];
          orow[col0 + 1] = acc[mt][nt][1] + b[1];
          orow[col0 + 2] = acc[mt][nt][2] + b[2];
          orow[col0 + 3] = acc[mt][nt][3] + b[3];
        } else if (col0 == 136) {
          orow[136] = acc[mt][nt][0] + baug[136];
        }
      }
    }
  }
  // no tail barriers: kernel ends after the masked stores
}

extern "C" void kernel_launch(void* const* d_in, const int* in_sizes, int n_in,
                              void* d_out, int out_size, void* d_ws, size_t ws_size,
                              hipStream_t stream) {
  const float* t        = (const float*)d_in[0];
  const float* state    = (const float*)d_in[1];
  const float* W0       = (const float*)d_in[2];
  const float* b0       = (const float*)d_in[3];
  const float* blkW1    = (const float*)d_in[4];
  const float* blkb1    = (const float*)d_in[5];
  const float* blkW2    = (const float*)d_in[6];
  const float* blkb2    = (const float*)d_in[7];
  const float* Wout     = (const float*)d_in[8];
  const float* bout     = (const float*)d_in[9];
  const float* lm_in_w  = (const float*)d_in[10];
  const float* lm_in_b  = (const float*)d_in[11];
  const float* lm_out_w = (const float*)d_in[12];
  const float* lm_out_b = (const float*)d_in[13];
  const float* ta_in_w  = (const float*)d_in[14];
  const float* ta_in_b  = (const float*)d_in[15];
  const float* ta_out_w = (const float*)d_in[16];
  const float* ta_out_b = (const float*)d_in[17];

  char* ws = (char*)d_ws;
  unsigned short* W0p   = (unsigned short*)ws;                   // 256*160*2   = 81920
  float*          b0p   = (float*)(ws + 81920);                  // 1024
  unsigned short* Waug  = (unsigned short*)(ws + 82944);         // 256*416*2   = 212992
  float*          baug  = (float*)(ws + 295936);                 // 1024
  unsigned short* W1b   = (unsigned short*)(ws + 296960);        // 4*256*256*2 = 524288
  unsigned short* W2b   = (unsigned short*)(ws + 821248);        // 524288  (total ~1.31 MB)

  prep_all<<<PB_END, 128, 0, stream>>>(t, W0, b0, Wout, bout,
                                       lm_in_w, lm_in_b, lm_out_w, lm_out_b,
                                       ta_in_w, ta_in_b, ta_out_w, ta_out_b,
                                       blkW1, blkW2,
                                       W0p, b0p, Waug, baug, W1b, W2b);

  int batch = in_sizes[1] / SDIM;               // 131072
  fused_odefunc<<<batch / MTILE, NTHR, 0, stream>>>(
      state, W0p, b0p, W1b, blkb1, W2b, blkb2, Waug, baug,
      (float*)d_out);
}